// Round 8
// baseline (197.475 us; speedup 1.0000x reference)
//
#include <hip/hip_runtime.h>

typedef __bf16 bf16x8 __attribute__((ext_vector_type(8)));
typedef float floatx4 __attribute__((ext_vector_type(4)));

#define B_ 4
#define S_ 1024
#define E_ 768
#define H_ 12
#define HD_ 64

__device__ __forceinline__ void async16(const void* g, void* l) {
  __builtin_amdgcn_global_load_lds((const __attribute__((address_space(1))) void*)g,
                                   (__attribute__((address_space(3))) void*)l, 16, 0, 0);
}

__device__ __forceinline__ floatx4 mfma16(bf16x8 a, bf16x8 b, floatx4 c) {
  return __builtin_amdgcn_mfma_f32_16x16x32_bf16(a, b, c, 0, 0, 0);
}

// ---------------- prep: fp32->bf16 casts (inputs + weights) ----------------
__global__ __launch_bounds__(256) void prep_kernel(
    const float* __restrict__ q, const float* __restrict__ k, const float* __restrict__ v,
    const float* __restrict__ w0, const float* __restrict__ w1,
    const float* __restrict__ w2, const float* __restrict__ w3,
    __bf16* __restrict__ xin, __bf16* __restrict__ wb) {
  const int bx = blockIdx.x;
  if (bx < 4608) {
    const int z = bx / 1536, xb = bx % 1536;
    const float* s = (z == 0) ? q : (z == 1) ? k : v;
    __bf16* d = xin + (size_t)z * (size_t)(B_ * S_ * E_);
    const size_t i8 = (size_t)xb * 256 + threadIdx.x;
    const float4* sp = (const float4*)s + i8 * 2;
    float4 a = sp[0], bb = sp[1];
    bf16x8 o;
    o[0] = (__bf16)a.x; o[1] = (__bf16)a.y; o[2] = (__bf16)a.z; o[3] = (__bf16)a.w;
    o[4] = (__bf16)bb.x; o[5] = (__bf16)bb.y; o[6] = (__bf16)bb.z; o[7] = (__bf16)bb.w;
    *(bf16x8*)(d + i8 * 8) = o;
  } else {
    const int t = bx - 4608;
    const int z = t / 288, xb = t % 288;
    const float* s = (z == 0) ? w0 : (z == 1) ? w1 : (z == 2) ? w2 : w3;
    __bf16* d = wb + (size_t)z * (size_t)(E_ * E_);
    const size_t i8 = (size_t)xb * 256 + threadIdx.x;
    const float4* sp = (const float4*)s + i8 * 2;
    float4 a = sp[0], bb = sp[1];
    bf16x8 o;
    o[0] = (__bf16)a.x; o[1] = (__bf16)a.y; o[2] = (__bf16)a.z; o[3] = (__bf16)a.w;
    o[4] = (__bf16)bb.x; o[5] = (__bf16)bb.y; o[6] = (__bf16)bb.z; o[7] = (__bf16)bb.w;
    *(bf16x8*)(d + i8 * 8) = o;
  }
}

// ---------------- QKV projection GEMM (128x128, BK=64, XOR-swizzled LDS) --------
// z=0 -> Qf [4096][768] scaled 0.125 ; z=1 -> Kf ; z=2 -> Vt [B,H,64,S] ;
// z=3 -> mask bitpack (memory-bound filler blocks, overlap with GEMM z=0..2).
__global__ __launch_bounds__(256, 3) void proj_qkv_kernel(
    const __bf16* __restrict__ Xq, const __bf16* __restrict__ Xk, const __bf16* __restrict__ Xv,
    const __bf16* __restrict__ Wq, const __bf16* __restrict__ Wk, const __bf16* __restrict__ Wv,
    const float* __restrict__ bq, const float* __restrict__ bk, const float* __restrict__ bv,
    const int* __restrict__ mask, unsigned long long* __restrict__ bmout,
    __bf16* __restrict__ Qf, __bf16* __restrict__ Kf, __bf16* __restrict__ Vt) {
  const int z = blockIdx.z;
  const int tid = threadIdx.x;

  if (z == 3) {  // ---- mask bitpack: 192 blocks, grid-stride over 4096 rows ----
    const int bid = blockIdx.x + 6 * blockIdx.y;  // 0..191
    const int wave = tid >> 6, lane = tid & 63;
#pragma unroll 1
    for (int row = bid; row < B_ * S_; row += 192) {
#pragma unroll
      for (int pass = 0; pass < 4; ++pass) {
        const int kk = pass * 256 + wave * 64 + lane;
        const int mv = mask[(size_t)row * S_ + kk];
        const unsigned long long bal = __ballot(mv != 0);
        if (lane == 0) bmout[(size_t)row * 16 + pass * 4 + wave] = bal;
      }
    }
    return;
  }

  const __bf16* X = (z == 0) ? Xq : (z == 1) ? Xk : Xv;
  const __bf16* W = (z == 0) ? Wq : (z == 1) ? Wk : Wv;
  const float* bias = (z == 0) ? bq : (z == 1) ? bk : bv;

  const int wave = tid >> 6, lane = tid & 63;
  const int l15 = lane & 15, quad = lane >> 4;
  const int wr = wave >> 1, wc = wave & 1;
  const int bm = blockIdx.y * 128, bn = blockIdx.x * 128;
  const int srl = lane >> 3, sch = lane & 7;  // staging sub-row, chunk

  // union: K-loop staging (As 16K + Bs 16K) / epilogue re-stage (4 x 64x72 bf16 = 36K)
  __shared__ alignas(16) unsigned char smem[4 * 64 * 72 * 2];
  __bf16* As = (__bf16*)smem;
  __bf16* Bs = (__bf16*)(smem + 16384);
  __bf16* ST = (__bf16*)smem + (size_t)wave * (64 * 72);

  floatx4 zf = {0.0f, 0.0f, 0.0f, 0.0f};
  floatx4 acc[4][4];
#pragma unroll
  for (int i = 0; i < 4; ++i)
#pragma unroll
    for (int j = 0; j < 4; ++j) acc[i][j] = zf;

  for (int kk = 0; kk < E_; kk += 64) {
#pragma unroll
    for (int c = 0; c < 4; ++c) {
      const int s = c * 4 + wave;           // segment 0..15
      const int row = s * 8 + srl;          // 0..127
      const int xo = (sch ^ (row & 7)) * 8; // swizzled source chunk offset
      async16(X + (size_t)(bm + row) * E_ + kk + xo, &As[s * 512]);
      async16(W + (size_t)(bn + row) * E_ + kk + xo, &Bs[s * 512]);
    }
    __syncthreads();
#pragma unroll
    for (int ks = 0; ks < 2; ++ks) {
      bf16x8 af[4], bfr[4];
#pragma unroll
      for (int i = 0; i < 4; ++i) {
        const int m = wr * 64 + i * 16 + l15;
        af[i] = *(const bf16x8*)&As[m * 64 + (((ks * 4 + quad) ^ (m & 7)) * 8)];
      }
#pragma unroll
      for (int j = 0; j < 4; ++j) {
        const int n = wc * 64 + j * 16 + l15;
        bfr[j] = *(const bf16x8*)&Bs[n * 64 + (((ks * 4 + quad) ^ (n & 7)) * 8)];
      }
#pragma unroll
      for (int i = 0; i < 4; ++i)
#pragma unroll
        for (int j = 0; j < 4; ++j)
          acc[i][j] = mfma16(af[i], bfr[j], acc[i][j]);
    }
    __syncthreads();
  }
  // after the final barrier all As/Bs reads are done; ST regions are wave-private

  if (z < 2) {
    __bf16* dst = (z == 0) ? Qf : Kf;
    const float sc = (z == 0) ? 0.125f : 1.0f;
#pragma unroll
    for (int j = 0; j < 4; ++j) {
      const float bval = bias[bn + wc * 64 + j * 16 + l15];
#pragma unroll
      for (int i = 0; i < 4; ++i)
#pragma unroll
        for (int r = 0; r < 4; ++r)
          ST[(i * 16 + quad * 4 + r) * 72 + j * 16 + l15] =
              (__bf16)((acc[i][j][r] + bval) * sc);
    }
#pragma unroll
    for (int t = 0; t < 8; ++t) {
      const int row = t * 8 + (lane >> 3), ch = lane & 7;
      bf16x8 vrow = *(const bf16x8*)&ST[row * 72 + ch * 8];
      *(bf16x8*)&dst[(size_t)(bm + wr * 64 + row) * E_ + bn + wc * 64 + ch * 8] = vrow;
    }
  } else {
#pragma unroll
    for (int j = 0; j < 4; ++j) {
      const float bval = bias[bn + wc * 64 + j * 16 + l15];
#pragma unroll
      for (int i = 0; i < 4; ++i)
#pragma unroll
        for (int r = 0; r < 4; ++r)
          ST[(j * 16 + l15) * 72 + i * 16 + quad * 4 + r] = (__bf16)(acc[i][j][r] + bval);
    }
    const int hh = (bn + wc * 64) >> 6;
    const int m0 = bm + wr * 64;
    const int bb = m0 >> 10, ss0 = m0 & 1023;
#pragma unroll
    for (int t = 0; t < 8; ++t) {
      const int d = t * 8 + (lane >> 3), ch = lane & 7;
      bf16x8 vrow = *(const bf16x8*)&ST[d * 72 + ch * 8];
      *(bf16x8*)&Vt[(((size_t)bb * H_ + hh) * HD_ + d) * S_ + ss0 + ch * 8] = vrow;
    }
  }
}

// ---------------- output projection GEMM (64x64, BK=64, XOR-swizzled LDS) -------
__global__ __launch_bounds__(256, 4) void proj_out_kernel(
    const __bf16* __restrict__ X, const __bf16* __restrict__ W,
    const float* __restrict__ bias, float* __restrict__ out) {
  const int tid = threadIdx.x;
  const int wave = tid >> 6, lane = tid & 63;
  const int l15 = lane & 15, quad = lane >> 4;
  const int wr = wave >> 1, wc = wave & 1;
  const int bm = blockIdx.y * 64, bn = blockIdx.x * 64;
  const int srl = lane >> 3, sch = lane & 7;

  __shared__ alignas(16) __bf16 As[64 * 64];
  __shared__ alignas(16) __bf16 Bs[64 * 64];

  floatx4 zf = {0.0f, 0.0f, 0.0f, 0.0f};
  floatx4 acc[2][2];
#pragma unroll
  for (int i = 0; i < 2; ++i)
#pragma unroll
    for (int j = 0; j < 2; ++j) acc[i][j] = zf;

  for (int kk = 0; kk < E_; kk += 64) {
#pragma unroll
    for (int c = 0; c < 2; ++c) {
      const int s = c * 4 + wave;           // 0..7
      const int row = s * 8 + srl;          // 0..63
      const int xo = (sch ^ (row & 7)) * 8;
      async16(X + (size_t)(bm + row) * E_ + kk + xo, &As[s * 512]);
      async16(W + (size_t)(bn + row) * E_ + kk + xo, &Bs[s * 512]);
    }
    __syncthreads();
#pragma unroll
    for (int ks = 0; ks < 2; ++ks) {
      bf16x8 af[2], bfr[2];
#pragma unroll
      for (int i = 0; i < 2; ++i) {
        const int m = wr * 32 + i * 16 + l15;
        af[i] = *(const bf16x8*)&As[m * 64 + (((ks * 4 + quad) ^ (m & 7)) * 8)];
      }
#pragma unroll
      for (int j = 0; j < 2; ++j) {
        const int n = wc * 32 + j * 16 + l15;
        bfr[j] = *(const bf16x8*)&Bs[n * 64 + (((ks * 4 + quad) ^ (n & 7)) * 8)];
      }
#pragma unroll
      for (int i = 0; i < 2; ++i)
#pragma unroll
        for (int j = 0; j < 2; ++j)
          acc[i][j] = mfma16(af[i], bfr[j], acc[i][j]);
    }
    __syncthreads();
  }

#pragma unroll
  for (int j = 0; j < 2; ++j) {
    const int n = bn + wc * 32 + j * 16 + l15;
    const float bval = bias[n];
#pragma unroll
    for (int i = 0; i < 2; ++i) {
#pragma unroll
      for (int r = 0; r < 4; ++r) {
        const int m = bm + wr * 32 + i * 16 + quad * 4 + r;
        out[(size_t)m * E_ + n] = acc[i][j][r] + bval;
      }
    }
  }
}

// ---------------- fused flash attention v3 + mask prefetch ----------------
#define MSHIFT 12.0f
#define PSTR 72
__global__ __launch_bounds__(256, 3) void attn_kernel(
    const __bf16* __restrict__ Qf, const __bf16* __restrict__ Kf,
    const __bf16* __restrict__ Vt, const unsigned long long* __restrict__ bmask,
    __bf16* __restrict__ XV) {
  const int tid = threadIdx.x;
  const int wave = tid >> 6, lane = tid & 63;
  const int l15 = lane & 15, quad = lane >> 4;
  const int bh = blockIdx.x;
  const int b = bh / H_, h = bh % H_;
  const int q0 = blockIdx.y * 64 + wave * 16;

  __shared__ alignas(16) __bf16 Kbuf[2][64 * 64];
  __shared__ alignas(16) __bf16 Vbuf[2][64 * 64];
  __shared__ alignas(16) __bf16 Ps[4 * 16 * PSTR];
  __bf16* Pw = &Ps[wave * 16 * PSTR];

  const __bf16* qb = Qf + ((size_t)b * S_ + q0) * E_ + h * HD_;
  bf16x8 af[2];
  af[0] = *(const bf16x8*)(qb + (size_t)l15 * E_ + quad * 8);
  af[1] = *(const bf16x8*)(qb + (size_t)l15 * E_ + 32 + quad * 8);

  const __bf16* kbase = Kf + (size_t)b * S_ * E_ + h * HD_;
  const __bf16* vbase = Vt + (size_t)bh * HD_ * S_;
  const unsigned long long* mbm = bmask + ((size_t)b * S_ + q0) * 16;

  const int srow = tid >> 3, sch = tid & 7;
#pragma unroll
  for (int c = 0; c < 2; ++c) {
    const int row = c * 32 + srow;
    const int xo = (sch ^ (row & 7)) * 8;
    async16(kbase + (size_t)row * E_ + xo, &Kbuf[0][(c * 256 + tid) * 8]);
    async16(vbase + (size_t)row * S_ + xo, &Vbuf[0][(c * 256 + tid) * 8]);
  }

  // prefetch mask bits for kt=0
  unsigned long long bmsh[4];
#pragma unroll
  for (int r = 0; r < 4; ++r)
    bmsh[r] = mbm[(size_t)(quad * 4 + r) * 16 + 0] >> l15;

  floatx4 zf = {0.0f, 0.0f, 0.0f, 0.0f};
  floatx4 o[4];
  float lrow[4];
#pragma unroll
  for (int jd = 0; jd < 4; ++jd) o[jd] = zf;
#pragma unroll
  for (int r = 0; r < 4; ++r) lrow[r] = 0.0f;

  for (int kt = 0; kt < 16; ++kt) {
    const int p = kt & 1;
    const int k0 = kt * 64;
    __syncthreads();

    if (kt < 15) {
      const int kn = k0 + 64;
#pragma unroll
      for (int c = 0; c < 2; ++c) {
        const int row = c * 32 + srow;
        const int xo = (sch ^ (row & 7)) * 8;
        async16(kbase + (size_t)(kn + row) * E_ + xo, &Kbuf[1 - p][(c * 256 + tid) * 8]);
        async16(vbase + (size_t)row * S_ + kn + xo, &Vbuf[1 - p][(c * 256 + tid) * 8]);
      }
    }

    // prefetch next iter's mask bits (off critical path; current in bmsh)
    unsigned long long bmnext[4];
    if (kt < 15) {
#pragma unroll
      for (int r = 0; r < 4; ++r)
        bmnext[r] = mbm[(size_t)(quad * 4 + r) * 16 + kt + 1] >> l15;
    }

    bf16x8 bk[4][2];
#pragma unroll
    for (int j = 0; j < 4; ++j) {
      const int key = j * 16 + l15;
#pragma unroll
      for (int ks = 0; ks < 2; ++ks)
        bk[j][ks] = *(const bf16x8*)&Kbuf[p][key * 64 + ((ks * 4 + quad) ^ (key & 7)) * 8];
    }
    bf16x8 bvf[4][2];
#pragma unroll
    for (int jd = 0; jd < 4; ++jd) {
      const int d = jd * 16 + l15;
#pragma unroll
      for (int ks2 = 0; ks2 < 2; ++ks2)
        bvf[jd][ks2] = *(const bf16x8*)&Vbuf[p][d * 64 + ((ks2 * 4 + quad) ^ (d & 7)) * 8];
    }

    floatx4 sc[4];
#pragma unroll
    for (int j = 0; j < 4; ++j) sc[j] = zf;
#pragma unroll
    for (int j = 0; j < 4; ++j) {
      sc[j] = mfma16(af[0], bk[j][0], sc[j]);
      sc[j] = mfma16(af[1], bk[j][1], sc[j]);
    }

#pragma unroll
    for (int j = 0; j < 4; ++j)
#pragma unroll
      for (int r = 0; r < 4; ++r) {
        float pv = __expf(sc[j][r] - MSHIFT);
        pv = ((bmsh[r] >> (j * 16)) & 1ull) ? pv : 0.0f;
        lrow[r] += pv;
        Pw[(quad * 4 + r) * PSTR + j * 16 + l15] = (__bf16)pv;
      }

#pragma unroll
    for (int ks2 = 0; ks2 < 2; ++ks2) {
      bf16x8 pa = *(const bf16x8*)&Pw[l15 * PSTR + ks2 * 32 + quad * 8];
#pragma unroll
      for (int jd = 0; jd < 4; ++jd) o[jd] = mfma16(pa, bvf[jd][ks2], o[jd]);
    }

    if (kt < 15) {
#pragma unroll
      for (int r = 0; r < 4; ++r) bmsh[r] = bmnext[r];
    }
  }

#pragma unroll
  for (int sh = 1; sh < 16; sh <<= 1)
#pragma unroll
    for (int r = 0; r < 4; ++r) lrow[r] += __shfl_xor(lrow[r], sh, 64);
  float linv[4];
#pragma unroll
  for (int r = 0; r < 4; ++r) linv[r] = (lrow[r] > 0.0f) ? (1.0f / lrow[r]) : 0.0f;
  __bf16* xbase = XV + ((size_t)b * S_ + q0) * E_ + h * HD_;
#pragma unroll
  for (int jd = 0; jd < 4; ++jd)
#pragma unroll
    for (int r = 0; r < 4; ++r)
      xbase[(size_t)(quad * 4 + r) * E_ + jd * 16 + l15] = (__bf16)(o[jd][r] * linv[r]);
}

extern "C" void kernel_launch(void* const* d_in, const int* in_sizes, int n_in,
                              void* d_out, int out_size, void* d_ws, size_t ws_size,
                              hipStream_t stream) {
  const float* query = (const float*)d_in[0];
  const float* key   = (const float*)d_in[1];
  const float* value = (const float*)d_in[2];
  const int*   mask  = (const int*)d_in[3];
  const float* Wq = (const float*)d_in[4];
  const float* bq = (const float*)d_in[5];
  const float* Wk = (const float*)d_in[6];
  const float* bk = (const float*)d_in[7];
  const float* Wv = (const float*)d_in[8];
  const float* bv = (const float*)d_in[9];
  const float* Wo = (const float*)d_in[10];
  const float* bo = (const float*)d_in[11];
  float* out = (float*)d_out;

  const size_t NX = (size_t)B_ * S_ * E_;  // 3145728
  const size_t NW = (size_t)E_ * E_;       // 589824
  __bf16* ws = (__bf16*)d_ws;
  __bf16* xq  = ws;
  __bf16* xk  = xq + NX;
  __bf16* xv  = xk + NX;
  __bf16* wqb = xv + NX;
  __bf16* wkb = wqb + NW;
  __bf16* wvb = wkb + NW;
  __bf16* wob = wvb + NW;
  __bf16* Qf  = wob + NW;
  __bf16* Kf  = Qf + NX;
  __bf16* Vt  = Kf + NX;
  __bf16* XVb = Vt + NX;
  unsigned long long* bmask = (unsigned long long*)(XVb + NX);  // 512 KB

  prep_kernel<<<dim3(5760), 256, 0, stream>>>(query, key, value, Wq, Wk, Wv, Wo,
                                              xq, wqb);
  proj_qkv_kernel<<<dim3(6, 32, 4), 256, 0, stream>>>(xq, xk, xv, wqb, wkb, wvb,
                                                      bq, bk, bv, mask, bmask,
                                                      Qf, Kf, Vt);
  attn_kernel<<<dim3(48, 16), 256, 0, stream>>>(Qf, Kf, Vt, bmask, XVb);
  proj_out_kernel<<<dim3(12, 64), 256, 0, stream>>>(XVb, wob, bo, out);
}

// Round 9
// 183.053 us; speedup vs baseline: 1.0788x; 1.0788x over previous
//
#include <hip/hip_runtime.h>

typedef __bf16 bf16x8 __attribute__((ext_vector_type(8)));
typedef float floatx4 __attribute__((ext_vector_type(4)));

#define B_ 4
#define S_ 1024
#define E_ 768
#define H_ 12
#define HD_ 64

__device__ __forceinline__ void async16(const void* g, void* l) {
  __builtin_amdgcn_global_load_lds((const __attribute__((address_space(1))) void*)g,
                                   (__attribute__((address_space(3))) void*)l, 16, 0, 0);
}

__device__ __forceinline__ floatx4 mfma16(bf16x8 a, bf16x8 b, floatx4 c) {
  return __builtin_amdgcn_mfma_f32_16x16x32_bf16(a, b, c, 0, 0, 0);
}

// ---------------- prep: fp32->bf16 casts + mask bitpack ----------------
__global__ __launch_bounds__(256) void prep_kernel(
    const float* __restrict__ q, const float* __restrict__ k, const float* __restrict__ v,
    const float* __restrict__ w0, const float* __restrict__ w1,
    const float* __restrict__ w2, const float* __restrict__ w3,
    const int* __restrict__ mask,
    __bf16* __restrict__ xin, __bf16* __restrict__ wb,
    unsigned long long* __restrict__ bm) {
  const int bx = blockIdx.x;
  if (bx < 4608) {
    const int z = bx / 1536, xb = bx % 1536;
    const float* s = (z == 0) ? q : (z == 1) ? k : v;
    __bf16* d = xin + (size_t)z * (size_t)(B_ * S_ * E_);
    const size_t i8 = (size_t)xb * 256 + threadIdx.x;
    const float4* sp = (const float4*)s + i8 * 2;
    float4 a = sp[0], bb = sp[1];
    bf16x8 o;
    o[0] = (__bf16)a.x; o[1] = (__bf16)a.y; o[2] = (__bf16)a.z; o[3] = (__bf16)a.w;
    o[4] = (__bf16)bb.x; o[5] = (__bf16)bb.y; o[6] = (__bf16)bb.z; o[7] = (__bf16)bb.w;
    *(bf16x8*)(d + i8 * 8) = o;
  } else if (bx < 5760) {
    const int t = bx - 4608;
    const int z = t / 288, xb = t % 288;
    const float* s = (z == 0) ? w0 : (z == 1) ? w1 : (z == 2) ? w2 : w3;
    __bf16* d = wb + (size_t)z * (size_t)(E_ * E_);
    const size_t i8 = (size_t)xb * 256 + threadIdx.x;
    const float4* sp = (const float4*)s + i8 * 2;
    float4 a = sp[0], bb = sp[1];
    bf16x8 o;
    o[0] = (__bf16)a.x; o[1] = (__bf16)a.y; o[2] = (__bf16)a.z; o[3] = (__bf16)a.w;
    o[4] = (__bf16)bb.x; o[5] = (__bf16)bb.y; o[6] = (__bf16)bb.z; o[7] = (__bf16)bb.w;
    *(bf16x8*)(d + i8 * 8) = o;
  } else {
    const int row = bx - 5760;  // 0..4095
    const int wave = threadIdx.x >> 6, lane = threadIdx.x & 63;
#pragma unroll
    for (int pass = 0; pass < 4; ++pass) {
      const int kk = pass * 256 + wave * 64 + lane;
      const int mv = mask[(size_t)row * S_ + kk];
      const unsigned long long bal = __ballot(mv != 0);
      if (lane == 0) bm[(size_t)row * 16 + pass * 4 + wave] = bal;
    }
  }
}

// ------- QKV projection GEMM (128x128, BK=64, double-buffered, XCD-local) -------
// grid (32, 6, 3): x = bm-tile (linear_id % 8 == bm%8 -> all bn-blocks of a row
// tile share one XCD's L2), y = bn-tile. z: 0->Qf (x0.125), 1->Kf, 2->Vt.
__global__ __launch_bounds__(256, 2) void proj_qkv_kernel(
    const __bf16* __restrict__ Xq, const __bf16* __restrict__ Xk, const __bf16* __restrict__ Xv,
    const __bf16* __restrict__ Wq, const __bf16* __restrict__ Wk, const __bf16* __restrict__ Wv,
    const float* __restrict__ bq, const float* __restrict__ bk, const float* __restrict__ bv,
    __bf16* __restrict__ Qf, __bf16* __restrict__ Kf, __bf16* __restrict__ Vt) {
  const int z = blockIdx.z;
  const __bf16* X = (z == 0) ? Xq : (z == 1) ? Xk : Xv;
  const __bf16* W = (z == 0) ? Wq : (z == 1) ? Wk : Wv;
  const float* bias = (z == 0) ? bq : (z == 1) ? bk : bv;

  const int tid = threadIdx.x;
  const int wave = tid >> 6, lane = tid & 63;
  const int l15 = lane & 15, quad = lane >> 4;
  const int wr = wave >> 1, wc = wave & 1;
  const int bm = blockIdx.x * 128, bn = blockIdx.y * 128;
  const int srl = lane >> 3, sch = lane & 7;  // staging sub-row, chunk

  // double-buffered staging: buf p at As+p*32768 (As 16K + Bs 16K each);
  // epilogue ST union (4 x 64x72 bf16 = 36 KB) reuses smem after final barrier
  __shared__ alignas(16) unsigned char smem[65536];
  __bf16* ST = (__bf16*)smem + (size_t)wave * (64 * 72);

  floatx4 zf = {0.0f, 0.0f, 0.0f, 0.0f};
  floatx4 acc[4][4];
#pragma unroll
  for (int i = 0; i < 4; ++i)
#pragma unroll
    for (int j = 0; j < 4; ++j) acc[i][j] = zf;

  // stage tile 0 into buf 0
#pragma unroll
  for (int c = 0; c < 4; ++c) {
    const int s = c * 4 + wave;           // segment 0..15
    const int row = s * 8 + srl;          // 0..127
    const int xo = (sch ^ (row & 7)) * 8;
    async16(X + (size_t)(bm + row) * E_ + xo, (__bf16*)smem + s * 512);
    async16(W + (size_t)(bn + row) * E_ + xo, (__bf16*)(smem + 16384) + s * 512);
  }

  for (int kt = 0; kt < 12; ++kt) {
    const int p = kt & 1;
    __bf16* As = (__bf16*)(smem + p * 32768);
    __bf16* Bs = (__bf16*)(smem + p * 32768 + 16384);
    __syncthreads();  // tile p staged (drains vm+lgkm), prev reads done

    if (kt < 11) {  // prefetch tile kt+1 into buf 1-p (in flight during compute)
      const int kk = (kt + 1) * 64;
      __bf16* An = (__bf16*)(smem + (1 - p) * 32768);
      __bf16* Bn = (__bf16*)(smem + (1 - p) * 32768 + 16384);
#pragma unroll
      for (int c = 0; c < 4; ++c) {
        const int s = c * 4 + wave;
        const int row = s * 8 + srl;
        const int xo = (sch ^ (row & 7)) * 8;
        async16(X + (size_t)(bm + row) * E_ + kk + xo, An + s * 512);
        async16(W + (size_t)(bn + row) * E_ + kk + xo, Bn + s * 512);
      }
    }

#pragma unroll
    for (int ks = 0; ks < 2; ++ks) {
      bf16x8 af[4], bfr[4];
#pragma unroll
      for (int i = 0; i < 4; ++i) {
        const int m = wr * 64 + i * 16 + l15;
        af[i] = *(const bf16x8*)&As[m * 64 + (((ks * 4 + quad) ^ (m & 7)) * 8)];
      }
#pragma unroll
      for (int j = 0; j < 4; ++j) {
        const int n = wc * 64 + j * 16 + l15;
        bfr[j] = *(const bf16x8*)&Bs[n * 64 + (((ks * 4 + quad) ^ (n & 7)) * 8)];
      }
#pragma unroll
      for (int i = 0; i < 4; ++i)
#pragma unroll
        for (int j = 0; j < 4; ++j)
          acc[i][j] = mfma16(af[i], bfr[j], acc[i][j]);
    }
  }
  __syncthreads();  // all LDS reads done before ST union reuse

  if (z < 2) {
    __bf16* dst = (z == 0) ? Qf : Kf;
    const float sc = (z == 0) ? 0.125f : 1.0f;
#pragma unroll
    for (int j = 0; j < 4; ++j) {
      const float bval = bias[bn + wc * 64 + j * 16 + l15];
#pragma unroll
      for (int i = 0; i < 4; ++i)
#pragma unroll
        for (int r = 0; r < 4; ++r)
          ST[(i * 16 + quad * 4 + r) * 72 + j * 16 + l15] =
              (__bf16)((acc[i][j][r] + bval) * sc);
    }
#pragma unroll
    for (int t = 0; t < 8; ++t) {
      const int row = t * 8 + (lane >> 3), ch = lane & 7;
      bf16x8 vrow = *(const bf16x8*)&ST[row * 72 + ch * 8];
      *(bf16x8*)&dst[(size_t)(bm + wr * 64 + row) * E_ + bn + wc * 64 + ch * 8] = vrow;
    }
  } else {
#pragma unroll
    for (int j = 0; j < 4; ++j) {
      const float bval = bias[bn + wc * 64 + j * 16 + l15];
#pragma unroll
      for (int i = 0; i < 4; ++i)
#pragma unroll
        for (int r = 0; r < 4; ++r)
          ST[(j * 16 + l15) * 72 + i * 16 + quad * 4 + r] = (__bf16)(acc[i][j][r] + bval);
    }
    const int hh = (bn + wc * 64) >> 6;
    const int m0 = bm + wr * 64;
    const int bb = m0 >> 10, ss0 = m0 & 1023;
#pragma unroll
    for (int t = 0; t < 8; ++t) {
      const int d = t * 8 + (lane >> 3), ch = lane & 7;
      bf16x8 vrow = *(const bf16x8*)&ST[d * 72 + ch * 8];
      *(bf16x8*)&Vt[(((size_t)bb * H_ + hh) * HD_ + d) * S_ + ss0 + ch * 8] = vrow;
    }
  }
}

// ------- output projection GEMM (64x64, BK=64, double-buffered, XCD-local) ------
// grid (64, 12): x = bm-tile (XCD-local per row-tile), y = bn-tile.
__global__ __launch_bounds__(256, 4) void proj_out_kernel(
    const __bf16* __restrict__ X, const __bf16* __restrict__ W,
    const float* __restrict__ bias, float* __restrict__ out) {
  const int tid = threadIdx.x;
  const int wave = tid >> 6, lane = tid & 63;
  const int l15 = lane & 15, quad = lane >> 4;
  const int wr = wave >> 1, wc = wave & 1;
  const int bm = blockIdx.x * 64, bn = blockIdx.y * 64;
  const int srl = lane >> 3, sch = lane & 7;

  __shared__ alignas(16) unsigned char smem[32768];  // 2 x (As 8K + Bs 8K)

  floatx4 zf = {0.0f, 0.0f, 0.0f, 0.0f};
  floatx4 acc[2][2];
#pragma unroll
  for (int i = 0; i < 2; ++i)
#pragma unroll
    for (int j = 0; j < 2; ++j) acc[i][j] = zf;

#pragma unroll
  for (int c = 0; c < 2; ++c) {
    const int s = c * 4 + wave;           // 0..7
    const int row = s * 8 + srl;          // 0..63
    const int xo = (sch ^ (row & 7)) * 8;
    async16(X + (size_t)(bm + row) * E_ + xo, (__bf16*)smem + s * 512);
    async16(W + (size_t)(bn + row) * E_ + xo, (__bf16*)(smem + 8192) + s * 512);
  }

  for (int kt = 0; kt < 12; ++kt) {
    const int p = kt & 1;
    __bf16* As = (__bf16*)(smem + p * 16384);
    __bf16* Bs = (__bf16*)(smem + p * 16384 + 8192);
    __syncthreads();

    if (kt < 11) {
      const int kk = (kt + 1) * 64;
      __bf16* An = (__bf16*)(smem + (1 - p) * 16384);
      __bf16* Bn = (__bf16*)(smem + (1 - p) * 16384 + 8192);
#pragma unroll
      for (int c = 0; c < 2; ++c) {
        const int s = c * 4 + wave;
        const int row = s * 8 + srl;
        const int xo = (sch ^ (row & 7)) * 8;
        async16(X + (size_t)(bm + row) * E_ + kk + xo, An + s * 512);
        async16(W + (size_t)(bn + row) * E_ + kk + xo, Bn + s * 512);
      }
    }

#pragma unroll
    for (int ks = 0; ks < 2; ++ks) {
      bf16x8 af[2], bfr[2];
#pragma unroll
      for (int i = 0; i < 2; ++i) {
        const int m = wr * 32 + i * 16 + l15;
        af[i] = *(const bf16x8*)&As[m * 64 + (((ks * 4 + quad) ^ (m & 7)) * 8)];
      }
#pragma unroll
      for (int j = 0; j < 2; ++j) {
        const int n = wc * 32 + j * 16 + l15;
        bfr[j] = *(const bf16x8*)&Bs[n * 64 + (((ks * 4 + quad) ^ (n & 7)) * 8)];
      }
#pragma unroll
      for (int i = 0; i < 2; ++i)
#pragma unroll
        for (int j = 0; j < 2; ++j)
          acc[i][j] = mfma16(af[i], bfr[j], acc[i][j]);
    }
  }

#pragma unroll
  for (int j = 0; j < 2; ++j) {
    const int n = bn + wc * 32 + j * 16 + l15;
    const float bval = bias[n];
#pragma unroll
    for (int i = 0; i < 2; ++i) {
#pragma unroll
      for (int r = 0; r < 4; ++r) {
        const int m = bm + wr * 32 + i * 16 + quad * 4 + r;
        out[(size_t)m * E_ + n] = acc[i][j][r] + bval;
      }
    }
  }
}

// ---------------- fused flash attention v3 + mask prefetch ----------------
#define MSHIFT 12.0f
#define PSTR 72
__global__ __launch_bounds__(256, 3) void attn_kernel(
    const __bf16* __restrict__ Qf, const __bf16* __restrict__ Kf,
    const __bf16* __restrict__ Vt, const unsigned long long* __restrict__ bmask,
    __bf16* __restrict__ XV) {
  const int tid = threadIdx.x;
  const int wave = tid >> 6, lane = tid & 63;
  const int l15 = lane & 15, quad = lane >> 4;
  const int bh = blockIdx.x;
  const int b = bh / H_, h = bh % H_;
  const int q0 = blockIdx.y * 64 + wave * 16;

  __shared__ alignas(16) __bf16 Kbuf[2][64 * 64];
  __shared__ alignas(16) __bf16 Vbuf[2][64 * 64];
  __shared__ alignas(16) __bf16 Ps[4 * 16 * PSTR];
  __bf16* Pw = &Ps[wave * 16 * PSTR];

  const __bf16* qb = Qf + ((size_t)b * S_ + q0) * E_ + h * HD_;
  bf16x8 af[2];
  af[0] = *(const bf16x8*)(qb + (size_t)l15 * E_ + quad * 8);
  af[1] = *(const bf16x8*)(qb + (size_t)l15 * E_ + 32 + quad * 8);

  const __bf16* kbase = Kf + (size_t)b * S_ * E_ + h * HD_;
  const __bf16* vbase = Vt + (size_t)bh * HD_ * S_;
  const unsigned long long* mbm = bmask + ((size_t)b * S_ + q0) * 16;

  const int srow = tid >> 3, sch = tid & 7;
#pragma unroll
  for (int c = 0; c < 2; ++c) {
    const int row = c * 32 + srow;
    const int xo = (sch ^ (row & 7)) * 8;
    async16(kbase + (size_t)row * E_ + xo, &Kbuf[0][(c * 256 + tid) * 8]);
    async16(vbase + (size_t)row * S_ + xo, &Vbuf[0][(c * 256 + tid) * 8]);
  }

  unsigned long long bmsh[4];
#pragma unroll
  for (int r = 0; r < 4; ++r)
    bmsh[r] = mbm[(size_t)(quad * 4 + r) * 16 + 0] >> l15;

  floatx4 zf = {0.0f, 0.0f, 0.0f, 0.0f};
  floatx4 o[4];
  float lrow[4];
#pragma unroll
  for (int jd = 0; jd < 4; ++jd) o[jd] = zf;
#pragma unroll
  for (int r = 0; r < 4; ++r) lrow[r] = 0.0f;

  for (int kt = 0; kt < 16; ++kt) {
    const int p = kt & 1;
    const int k0 = kt * 64;
    __syncthreads();

    if (kt < 15) {
      const int kn = k0 + 64;
#pragma unroll
      for (int c = 0; c < 2; ++c) {
        const int row = c * 32 + srow;
        const int xo = (sch ^ (row & 7)) * 8;
        async16(kbase + (size_t)(kn + row) * E_ + xo, &Kbuf[1 - p][(c * 256 + tid) * 8]);
        async16(vbase + (size_t)row * S_ + kn + xo, &Vbuf[1 - p][(c * 256 + tid) * 8]);
      }
    }

    unsigned long long bmnext[4];
    if (kt < 15) {
#pragma unroll
      for (int r = 0; r < 4; ++r)
        bmnext[r] = mbm[(size_t)(quad * 4 + r) * 16 + kt + 1] >> l15;
    }

    bf16x8 bk[4][2];
#pragma unroll
    for (int j = 0; j < 4; ++j) {
      const int key = j * 16 + l15;
#pragma unroll
      for (int ks = 0; ks < 2; ++ks)
        bk[j][ks] = *(const bf16x8*)&Kbuf[p][key * 64 + ((ks * 4 + quad) ^ (key & 7)) * 8];
    }
    bf16x8 bvf[4][2];
#pragma unroll
    for (int jd = 0; jd < 4; ++jd) {
      const int d = jd * 16 + l15;
#pragma unroll
      for (int ks2 = 0; ks2 < 2; ++ks2)
        bvf[jd][ks2] = *(const bf16x8*)&Vbuf[p][d * 64 + ((ks2 * 4 + quad) ^ (d & 7)) * 8];
    }

    floatx4 sc[4];
#pragma unroll
    for (int j = 0; j < 4; ++j) sc[j] = zf;
#pragma unroll
    for (int j = 0; j < 4; ++j) {
      sc[j] = mfma16(af[0], bk[j][0], sc[j]);
      sc[j] = mfma16(af[1], bk[j][1], sc[j]);
    }

#pragma unroll
    for (int j = 0; j < 4; ++j)
#pragma unroll
      for (int r = 0; r < 4; ++r) {
        float pv = __expf(sc[j][r] - MSHIFT);
        pv = ((bmsh[r] >> (j * 16)) & 1ull) ? pv : 0.0f;
        lrow[r] += pv;
        Pw[(quad * 4 + r) * PSTR + j * 16 + l15] = (__bf16)pv;
      }

#pragma unroll
    for (int ks2 = 0; ks2 < 2; ++ks2) {
      bf16x8 pa = *(const bf16x8*)&Pw[l15 * PSTR + ks2 * 32 + quad * 8];
#pragma unroll
      for (int jd = 0; jd < 4; ++jd) o[jd] = mfma16(pa, bvf[jd][ks2], o[jd]);
    }

    if (kt < 15) {
#pragma unroll
      for (int r = 0; r < 4; ++r) bmsh[r] = bmnext[r];
    }
  }

#pragma unroll
  for (int sh = 1; sh < 16; sh <<= 1)
#pragma unroll
    for (int r = 0; r < 4; ++r) lrow[r] += __shfl_xor(lrow[r], sh, 64);
  float linv[4];
#pragma unroll
  for (int r = 0; r < 4; ++r) linv[r] = (lrow[r] > 0.0f) ? (1.0f / lrow[r]) : 0.0f;
  __bf16* xbase = XV + ((size_t)b * S_ + q0) * E_ + h * HD_;
#pragma unroll
  for (int jd = 0; jd < 4; ++jd)
#pragma unroll
    for (int r = 0; r < 4; ++r)
      xbase[(size_t)(quad * 4 + r) * E_ + jd * 16 + l15] = (__bf16)(o[jd][r] * linv[r]);
}

extern "C" void kernel_launch(void* const* d_in, const int* in_sizes, int n_in,
                              void* d_out, int out_size, void* d_ws, size_t ws_size,
                              hipStream_t stream) {
  const float* query = (const float*)d_in[0];
  const float* key   = (const float*)d_in[1];
  const float* value = (const float*)d_in[2];
  const int*   mask  = (const int*)d_in[3];
  const float* Wq = (const float*)d_in[4];
  const float* bq = (const float*)d_in[5];
  const float* Wk = (const float*)d_in[6];
  const float* bk = (const float*)d_in[7];
  const float* Wv = (const float*)d_in[8];
  const float* bv = (const float*)d_in[9];
  const float* Wo = (const float*)d_in[10];
  const float* bo = (const float*)d_in[11];
  float* out = (float*)d_out;

  const size_t NX = (size_t)B_ * S_ * E_;  // 3145728
  const size_t NW = (size_t)E_ * E_;       // 589824
  __bf16* ws = (__bf16*)d_ws;
  __bf16* xq  = ws;
  __bf16* xk  = xq + NX;
  __bf16* xv  = xk + NX;
  __bf16* wqb = xv + NX;
  __bf16* wkb = wqb + NW;
  __bf16* wvb = wkb + NW;
  __bf16* wob = wvb + NW;
  __bf16* Qf  = wob + NW;
  __bf16* Kf  = Qf + NX;
  __bf16* Vt  = Kf + NX;
  __bf16* XVb = Vt + NX;
  unsigned long long* bmask = (unsigned long long*)(XVb + NX);  // 512 KB

  prep_kernel<<<dim3(9856), 256, 0, stream>>>(query, key, value, Wq, Wk, Wv, Wo,
                                              mask, xq, wqb, bmask);
  proj_qkv_kernel<<<dim3(32, 6, 3), 256, 0, stream>>>(xq, xk, xv, wqb, wkb, wvb,
                                                      bq, bk, bv, Qf, Kf, Vt);
  attn_kernel<<<dim3(48, 16), 256, 0, stream>>>(Qf, Kf, Vt, bmask, XVb);
  proj_out_kernel<<<dim3(64, 12), 256, 0, stream>>>(XVb, wob, bo, out);
}